// Round 10
// baseline (202.984 us; speedup 1.0000x reference)
//
#include <hip/hip_runtime.h>

#define B_ 4
#define N0_ 50000
#define N1_ 25000
#define N2_ 12500
#define E0_ 800000
#define E1_ 400000
#define CIN_ 32
#define CS_ 16
#define COUT_ 32
#define EPS_ 1e-5f
#define CAP_ 80               // single bucket, row = 320 B = 5 lines, line-aligned
#define ROW_ CAP_
#define RCAP0_ 14336          // per (slice,rep) region, L1
#define RCAP1_ 8192           // L2
#define NREP_ 8
#define CPAD_ 16              // rcnt counter stride in ints = 64B
#define SPLITB_ 512
#define SST1_ 3200            // slice stride for cur1 (>= ceil-local-max)
#define SST2_ 1600            // slice stride for cur2

// interleaved slice: matches XCD of consumer block (n/4) under round-robin dispatch
__device__ __forceinline__ int slice_of(int d) { return (d >> 2) & 7; }
// slice-major cursor index: one slice's counters contiguous -> no cross-XCD line sharing
__device__ __forceinline__ int curix(int d, int sst) {
    return ((d >> 2) & 7) * sst + ((d >> 5) << 2) + (d & 3);
}

__device__ __forceinline__ float sigmoidf_(float x) {
    return __builtin_amdgcn_rcpf(1.0f + __expf(-x));
}

// ---- prep: qv = Q@Watt[0:C], kv = K@Watt[C:2C], se = We . Watt[2C:3C] ----
__global__ void prep_kernel(const float* __restrict__ Q1, const float* __restrict__ K1,
                            const float* __restrict__ Watt1,
                            const float* __restrict__ Q2, const float* __restrict__ K2,
                            const float* __restrict__ Watt2,
                            const float* __restrict__ We1, const float* __restrict__ We2,
                            float* __restrict__ qv1, float* __restrict__ kv1,
                            float* __restrict__ qv2, float* __restrict__ kv2,
                            float* __restrict__ se) {
    int t = threadIdx.x;
    if (t < CS_) {
        float q = 0.f, k = 0.f;
        for (int c = 0; c < CS_; ++c) {
            q += Q1[t * CS_ + c] * Watt1[c];
            k += K1[t * CS_ + c] * Watt1[CS_ + c];
        }
        qv1[t] = q; kv1[t] = k;
    }
    if (t < COUT_) {
        float q = 0.f, k = 0.f;
        for (int c = 0; c < COUT_; ++c) {
            q += Q2[t * COUT_ + c] * Watt2[c];
            k += K2[t * COUT_ + c] * Watt2[COUT_ + c];
        }
        qv2[t] = q; kv2[t] = k;
    }
    if (t == 0) {
        float s1 = 0.f, s2 = 0.f;
        for (int c = 0; c < CS_; ++c) s1 += We1[c] * Watt1[2 * CS_ + c];
        for (int c = 0; c < COUT_; ++c) s2 += We2[c] * Watt2[2 * COUT_ + c];
        se[0] = s1; se[1] = s2;
    }
}

// ---- pass 1: per-block two-pass compaction into 8 dst-slices x 8 reps ----
template <int RCAP>
__device__ __forceinline__ void split_dev(const int* __restrict__ ei, const float* __restrict__ ew,
                                          int E, int* __restrict__ rcnt,
                                          unsigned* __restrict__ A, unsigned short* __restrict__ C,
                                          int bid, int nblocks) {
    __shared__ int lcnt[8];
    __shared__ int lbase[8];
    int tid = threadIdx.x;
    int lane = tid & 63;
    int rep = bid & (NREP_ - 1);
    int per = (E + nblocks - 1) / nblocks;
    int s0 = bid * per;
    int s1 = min(E, s0 + per);
    int niter = (s1 - s0 + 255) >> 8;
    if (tid < 8) lcnt[tid] = 0;
    __syncthreads();
    for (int i = 0; i < niter; ++i) {
        int e = s0 + i * 256 + tid;
        int slice = (e < s1) ? slice_of(ei[E + e]) : -1;
#pragma unroll
        for (int sl = 0; sl < 8; ++sl) {
            unsigned long long m = __ballot(slice == sl);
            if (m && lane == __ffsll(m) - 1) atomicAdd(&lcnt[sl], (int)__popcll(m));
        }
    }
    __syncthreads();
    if (tid < 8) {
        lbase[tid] = atomicAdd(&rcnt[(tid * NREP_ + rep) * CPAD_], lcnt[tid]);
        lcnt[tid] = 0;
    }
    __syncthreads();
    for (int i = 0; i < niter; ++i) {
        int e = s0 + i * 256 + tid;
        int d = 0, s = 0, slice = -1;
        float w = 0.f;
        if (e < s1) {
            d = ei[E + e];
            s = ei[e];
            w = ew[e];
            slice = slice_of(d);
        }
        int pos = 0;
#pragma unroll
        for (int sl = 0; sl < 8; ++sl) {
            unsigned long long m = __ballot(slice == sl);
            if (!m) continue;
            int leader = __ffsll(m) - 1;
            int base = 0;
            if (lane == leader) base = atomicAdd(&lcnt[sl], (int)__popcll(m));
            base = __shfl(base, leader);
            if (slice == sl) pos = base + (int)__popcll(m & ((1ull << lane) - 1ull));
        }
        if (slice >= 0) {
            int gpos = lbase[slice] + pos;
            if (gpos < RCAP) {
                int idx = (slice * NREP_ + rep) * RCAP + gpos;
                A[idx] = (unsigned)d | ((unsigned)s << 16);
                C[idx] = (unsigned short)((__float_as_uint(w) + 0x8000u) >> 16);
            }
        }
    }
}

__global__ void split_both(const int* __restrict__ ei0, const float* __restrict__ ew0,
                           const int* __restrict__ ei1, const float* __restrict__ ew1,
                           int* __restrict__ rcnt0, int* __restrict__ rcnt1,
                           unsigned* __restrict__ A0, unsigned short* __restrict__ C0,
                           unsigned* __restrict__ A1, unsigned short* __restrict__ C1) {
    if (blockIdx.x < SPLITB_)
        split_dev<RCAP0_>(ei0, ew0, E0_, rcnt0, A0, C0, blockIdx.x, SPLITB_);
    else
        split_dev<RCAP1_>(ei1, ew1, E1_, rcnt1, A1, C1, blockIdx.x - SPLITB_, SPLITB_);
}

// ---- pass 2: pure slice-local binning, 4 B slots = {bf16(w) hi16, src lo16} ----
__global__ void scatter_bin(const int* __restrict__ rcnt0, const unsigned* __restrict__ A0,
                            const unsigned short* __restrict__ C0,
                            int* __restrict__ cur0, unsigned* __restrict__ buf0,
                            const int* __restrict__ rcnt1, const unsigned* __restrict__ A1,
                            const unsigned short* __restrict__ C1,
                            int* __restrict__ cur1b, unsigned* __restrict__ buf1) {
    int half = blockIdx.x >= 1024;
    int bid = blockIdx.x & 1023;
    int slice = bid & 7;        // 1024 % 8 == 0 -> XCD alignment preserved for both halves
    int chunk = bid >> 3;
    const int nch = 128;
    int tid = threadIdx.x;
    const int* rc = half ? rcnt1 : rcnt0;
    const unsigned* A = half ? A1 : A0;
    const unsigned short* C = half ? C1 : C0;
    int* cur = half ? cur1b : cur0;
    unsigned* buf = half ? buf1 : buf0;
    int RCAP = half ? RCAP1_ : RCAP0_;
    int sst = half ? SST2_ : SST1_;
#pragma unroll
    for (int rep = 0; rep < NREP_; ++rep) {
        int cnt = rc[(slice * NREP_ + rep) * CPAD_];
        if (cnt > RCAP) cnt = RCAP;
        int base = (slice * NREP_ + rep) * RCAP;
        for (int i = chunk * 256 + tid; i < cnt; i += nch * 256) {
            unsigned a = A[base + i];
            int d = a & 0xffff;
            unsigned s = a >> 16;
            unsigned wu = (unsigned)C[base + i];
            int p = atomicAdd(&cur[curix(d, sst)], 1);
            if (p < CAP_)
                buf[(size_t)d * ROW_ + p] = (wu << 16) | s;
        }
    }
}

// ---- layer1 node transform: bf16 xs rows + fp32 xd + per-node att scalars ----
__global__ void node_xform1(const float* __restrict__ X, const int* __restrict__ res,
                            const float* __restrict__ Wn,
                            const float* __restrict__ qv, const float* __restrict__ kv,
                            unsigned short* __restrict__ xsb, float* __restrict__ xd_t,
                            float* __restrict__ aj, float* __restrict__ ai) {
    int lane = threadIdx.x & 63;
    int n = blockIdx.x * (blockDim.x >> 6) + (threadIdx.x >> 6);
    if (n >= N1_) return;
    int b = lane >> 4;
    int c = lane & 15;
    int rn = res[n];
    const float4* Xs4 = (const float4*)(X + ((size_t)b * N0_ + n) * CIN_);
    const float4* Xd4 = (const float4*)(X + ((size_t)b * N0_ + rn) * CIN_);
    float s = 0.f, d = 0.f;
#pragma unroll
    for (int k4 = 0; k4 < CIN_ / 4; ++k4) {
        float4 xs4 = Xs4[k4];
        float4 xd4 = Xd4[k4];
        int k = 4 * k4;
        float w0 = Wn[(k + 0) * CS_ + c], w1 = Wn[(k + 1) * CS_ + c];
        float w2 = Wn[(k + 2) * CS_ + c], w3 = Wn[(k + 3) * CS_ + c];
        s += xs4.x * w0 + xs4.y * w1 + xs4.z * w2 + xs4.w * w3;
        d += xd4.x * w0 + xd4.y * w1 + xd4.z * w2 + xd4.w * w3;
    }
    xsb[(size_t)n * 64 + lane] = (unsigned short)((__float_as_uint(s) + 0x8000u) >> 16);
    xd_t[(size_t)n * 64 + lane] = d;
    float p = s * qv[c];
    float q = d * kv[c];
#pragma unroll
    for (int m = 1; m < 16; m <<= 1) {
        p += __shfl_xor(p, m, 16);
        q += __shfl_xor(q, m, 16);
    }
    if (c == 0) {
        aj[n * 4 + b] = p;
        ai[n * 4 + b] = q;
    }
}

// ---- layer1 fused edge+epilogue: att computed in fp32 here ----
__global__ void edge_fused1(const int* __restrict__ cur, const unsigned* __restrict__ buf,
                            const unsigned short* __restrict__ xsb,
                            const float* __restrict__ xd_t,
                            const float* __restrict__ aj, const float* __restrict__ ai,
                            const float* __restrict__ sep, const float* __restrict__ batt,
                            const float* __restrict__ We,
                            const float* __restrict__ Wc, const float* __restrict__ bc,
                            float* __restrict__ h_t) {
    int lane = threadIdx.x & 63;
    int n = blockIdx.x * (blockDim.x >> 6) + (threadIdx.x >> 6);
    if (n >= N1_) return;
    int b = lane >> 4;
    int c = lane & 15;
    float wec = We[c];
    float se1 = sep[0];
    float aivb = ai[n * 4 + b] + batt[0];
    float acc = 0.f;
    int cnt = cur[curix(n, SST1_)];
    if (cnt > CAP_) cnt = CAP_;
    const unsigned* bp = buf + (size_t)n * ROW_;
    int i = 0;
    for (; i + 4 <= cnt; i += 4) {
        unsigned v0 = bp[i], v1 = bp[i + 1], v2 = bp[i + 2], v3 = bp[i + 3];
        int s0 = v0 & 0xffff, s1 = v1 & 0xffff, s2 = v2 & 0xffff, s3 = v3 & 0xffff;
        float w0 = __uint_as_float(v0 & 0xffff0000u);
        float w1 = __uint_as_float(v1 & 0xffff0000u);
        float w2 = __uint_as_float(v2 & 0xffff0000u);
        float w3 = __uint_as_float(v3 & 0xffff0000u);
        float aj0 = aj[s0 * 4 + b], aj1 = aj[s1 * 4 + b];
        float aj2 = aj[s2 * 4 + b], aj3 = aj[s3 * 4 + b];
        float xj0 = __uint_as_float((unsigned)xsb[(size_t)s0 * 64 + lane] << 16);
        float xj1 = __uint_as_float((unsigned)xsb[(size_t)s1 * 64 + lane] << 16);
        float xj2 = __uint_as_float((unsigned)xsb[(size_t)s2 * 64 + lane] << 16);
        float xj3 = __uint_as_float((unsigned)xsb[(size_t)s3 * 64 + lane] << 16);
        acc += sigmoidf_(aj0 + aivb + w0 * se1) * sigmoidf_(w0 * wec) * xj0;
        acc += sigmoidf_(aj1 + aivb + w1 * se1) * sigmoidf_(w1 * wec) * xj1;
        acc += sigmoidf_(aj2 + aivb + w2 * se1) * sigmoidf_(w2 * wec) * xj2;
        acc += sigmoidf_(aj3 + aivb + w3 * se1) * sigmoidf_(w3 * wec) * xj3;
    }
    for (; i < cnt; ++i) {
        unsigned v0 = bp[i];
        int s0 = v0 & 0xffff;
        float w0 = __uint_as_float(v0 & 0xffff0000u);
        float aj0 = aj[s0 * 4 + b];
        float xj0 = __uint_as_float((unsigned)xsb[(size_t)s0 * 64 + lane] << 16);
        acc += sigmoidf_(aj0 + aivb + w0 * se1) * sigmoidf_(w0 * wec) * xj0;
    }
    // fused epilogue
    float xv = xd_t[(size_t)n * 64 + lane];
    float o = bc[c];
#pragma unroll
    for (int k = 0; k < CS_; ++k) {
        o += __shfl(xv, k, 16) * Wc[k * CS_ + c];
        o += __shfl(acc, k, 16) * Wc[(CS_ + k) * CS_ + c];
    }
    float s = o, sq = o * o;
#pragma unroll
    for (int m = 1; m < 64; m <<= 1) {
        s += __shfl_xor(s, m);
        sq += __shfl_xor(sq, m);
    }
    float mean = s * (1.f / 64.f);
    float var = (sq - 64.f * mean * mean) * (1.f / 63.f);
    float inv = __builtin_amdgcn_rsqf(var + EPS_);
    float v = xv + (o - mean) * inv;
    h_t[(size_t)n * 64 + lane] = v > 0.f ? v : 0.01f * v;
}

// ---- layer2 node transform ----
__global__ void node_xform2(const float* __restrict__ h_t, const int* __restrict__ res,
                            const float* __restrict__ Wn,
                            const float* __restrict__ qv, const float* __restrict__ kv,
                            unsigned short* __restrict__ xsb, float* __restrict__ xd_t,
                            float* __restrict__ aj, float* __restrict__ ai) {
    int lane = threadIdx.x & 63;
    int n = blockIdx.x * (blockDim.x >> 6) + (threadIdx.x >> 6);
    if (n >= N2_) return;
    int bl = lane >> 5;
    int c = lane & 31;
    int rn = res[n];
    float qc = qv[c], kc = kv[c];
#pragma unroll
    for (int j = 0; j < 2; ++j) {
        int b = bl + 2 * j;
        const float* hs = h_t + (size_t)n * 64 + b * 16;
        const float* hd = h_t + (size_t)rn * 64 + b * 16;
        float s = 0.f, d = 0.f;
#pragma unroll
        for (int k = 0; k < CS_; ++k) {
            float w = Wn[k * COUT_ + c];
            s += hs[k] * w;
            d += hd[k] * w;
        }
        xsb[(size_t)n * 128 + b * 32 + c] = (unsigned short)((__float_as_uint(s) + 0x8000u) >> 16);
        xd_t[(size_t)n * 128 + b * 32 + c] = d;
        float p = s * qc;
        float q = d * kc;
#pragma unroll
        for (int m = 1; m < 32; m <<= 1) {
            p += __shfl_xor(p, m, 32);
            q += __shfl_xor(q, m, 32);
        }
        if (c == 0) {
            aj[n * 4 + b] = p;
            ai[n * 4 + b] = q;
        }
    }
}

// ---- layer2 fused edge+epilogue -> d_out ----
__global__ void edge_fused2(const int* __restrict__ cur, const unsigned* __restrict__ buf,
                            const unsigned short* __restrict__ xsb,
                            const float* __restrict__ xd_t,
                            const float* __restrict__ aj, const float* __restrict__ ai,
                            const float* __restrict__ sep, const float* __restrict__ batt,
                            const float* __restrict__ We,
                            const float* __restrict__ Wc, const float* __restrict__ bc,
                            float* __restrict__ out) {
    int lane = threadIdx.x & 63;
    int n = blockIdx.x * (blockDim.x >> 6) + (threadIdx.x >> 6);
    if (n >= N2_) return;
    int bl = lane >> 5;
    int c = lane & 31;
    float wec = We[c];
    float se2 = sep[0];
    float b0 = batt[0];
    float aiv0 = ai[n * 4 + bl] + b0;
    float aiv1 = ai[n * 4 + bl + 2] + b0;
    float acc0 = 0.f, acc1 = 0.f;
    int cnt = cur[curix(n, SST2_)];
    if (cnt > CAP_) cnt = CAP_;
    const unsigned* bp = buf + (size_t)n * ROW_;
    int i = 0;
    for (; i + 2 <= cnt; i += 2) {
        unsigned v0 = bp[i], v1 = bp[i + 1];
        int s0 = v0 & 0xffff, s1 = v1 & 0xffff;
        float w0 = __uint_as_float(v0 & 0xffff0000u);
        float w1 = __uint_as_float(v1 & 0xffff0000u);
        float aj00 = aj[s0 * 4 + bl], aj01 = aj[s0 * 4 + bl + 2];
        float aj10 = aj[s1 * 4 + bl], aj11 = aj[s1 * 4 + bl + 2];
        float xj00 = __uint_as_float((unsigned)xsb[(size_t)s0 * 128 + lane] << 16);
        float xj01 = __uint_as_float((unsigned)xsb[(size_t)s0 * 128 + 64 + lane] << 16);
        float xj10 = __uint_as_float((unsigned)xsb[(size_t)s1 * 128 + lane] << 16);
        float xj11 = __uint_as_float((unsigned)xsb[(size_t)s1 * 128 + 64 + lane] << 16);
        float g0 = sigmoidf_(w0 * wec);
        float g1 = sigmoidf_(w1 * wec);
        float t0 = w0 * se2, t1 = w1 * se2;
        acc0 += sigmoidf_(aj00 + aiv0 + t0) * g0 * xj00;
        acc1 += sigmoidf_(aj01 + aiv1 + t0) * g0 * xj01;
        acc0 += sigmoidf_(aj10 + aiv0 + t1) * g1 * xj10;
        acc1 += sigmoidf_(aj11 + aiv1 + t1) * g1 * xj11;
    }
    if (i < cnt) {
        unsigned v0 = bp[i];
        int s0 = v0 & 0xffff;
        float w0 = __uint_as_float(v0 & 0xffff0000u);
        float aj00 = aj[s0 * 4 + bl], aj01 = aj[s0 * 4 + bl + 2];
        float xj00 = __uint_as_float((unsigned)xsb[(size_t)s0 * 128 + lane] << 16);
        float xj01 = __uint_as_float((unsigned)xsb[(size_t)s0 * 128 + 64 + lane] << 16);
        float g0 = sigmoidf_(w0 * wec);
        float t0 = w0 * se2;
        acc0 += sigmoidf_(aj00 + aiv0 + t0) * g0 * xj00;
        acc1 += sigmoidf_(aj01 + aiv1 + t0) * g0 * xj01;
    }
    // fused epilogue
    float xv0 = xd_t[(size_t)n * 128 + lane];
    float xv1 = xd_t[(size_t)n * 128 + 64 + lane];
    float o0 = bc[c], o1 = o0;
#pragma unroll
    for (int k = 0; k < COUT_; ++k) {
        float w1 = Wc[k * COUT_ + c];
        float w2 = Wc[(COUT_ + k) * COUT_ + c];
        o0 += __shfl(xv0, k, 32) * w1 + __shfl(acc0, k, 32) * w2;
        o1 += __shfl(xv1, k, 32) * w1 + __shfl(acc1, k, 32) * w2;
    }
    float s = o0 + o1, sq = o0 * o0 + o1 * o1;
#pragma unroll
    for (int m = 1; m < 64; m <<= 1) {
        s += __shfl_xor(s, m);
        sq += __shfl_xor(sq, m);
    }
    float mean = s * (1.f / 128.f);
    float var = (sq - 128.f * mean * mean) * (1.f / 127.f);
    float inv = __builtin_amdgcn_rsqf(var + EPS_);
    float v0 = xv0 + (o0 - mean) * inv;
    float v1 = xv1 + (o1 - mean) * inv;
    out[((size_t)bl * N2_ + n) * COUT_ + c] = v0 > 0.f ? v0 : 0.01f * v0;
    out[((size_t)(bl + 2) * N2_ + n) * COUT_ + c] = v1 > 0.f ? v1 : 0.01f * v1;
}

extern "C" void kernel_launch(void* const* d_in, const int* in_sizes, int n_in,
                              void* d_out, int out_size, void* d_ws, size_t ws_size,
                              hipStream_t stream) {
    (void)in_sizes; (void)n_in; (void)out_size; (void)ws_size;
    const float* X     = (const float*)d_in[0];
    const int*   ei0   = (const int*)d_in[1];
    const float* ew0   = (const float*)d_in[2];
    const int*   rn0   = (const int*)d_in[3];
    const int*   ei1   = (const int*)d_in[4];
    const float* ew1   = (const float*)d_in[5];
    const int*   rn1   = (const int*)d_in[6];
    const float* Wn1   = (const float*)d_in[7];
    const float* We1   = (const float*)d_in[8];
    const float* Q1    = (const float*)d_in[9];
    const float* K1    = (const float*)d_in[10];
    const float* Watt1 = (const float*)d_in[11];
    const float* batt1 = (const float*)d_in[12];
    const float* Wc1   = (const float*)d_in[13];
    const float* bc1   = (const float*)d_in[14];
    const float* Wn2   = (const float*)d_in[15];
    const float* We2   = (const float*)d_in[16];
    const float* Q2    = (const float*)d_in[17];
    const float* K2    = (const float*)d_in[18];
    const float* Watt2 = (const float*)d_in[19];
    const float* batt2 = (const float*)d_in[20];
    const float* Wc2   = (const float*)d_in[21];
    const float* bc2   = (const float*)d_in[22];

    // ---- workspace layout ----
    const size_t BUF = (size_t)B_ * N1_ * CS_;  // 1.6M elements
    float* ws  = (float*)d_ws;
    float* S0  = ws;             // xd1 -> h
    float* S1  = S0 + BUF;       // xd2
    unsigned short* S2 = (unsigned short*)(S1 + BUF);  // xsb (bf16), L1 then L2
    float* aj1 = (float*)(S2 + BUF);
    float* ai1 = aj1 + (size_t)N1_ * 4;
    float* aj2 = ai1 + (size_t)N1_ * 4;
    float* ai2 = aj2 + (size_t)N2_ * 4;
    unsigned* ebuf1 = (unsigned*)(ai2 + (size_t)N2_ * 4);   // N1*ROW_ u32 = 8 MB
    unsigned* ebuf2 = ebuf1 + (size_t)N1_ * ROW_;           // N2*ROW_ u32 = 4 MB
    int* cur1  = (int*)(ebuf2 + (size_t)N2_ * ROW_);        // 8*SST1_
    int* cur2  = cur1 + 8 * SST1_;                          // 8*SST2_
    int* rcnt0 = cur2 + 8 * SST2_;                          // 64*CPAD_
    int* rcnt1 = rcnt0 + 64 * CPAD_;                        // 64*CPAD_
    unsigned* A0 = (unsigned*)(rcnt1 + 64 * CPAD_);
    unsigned* A1 = A0 + (size_t)64 * RCAP0_;
    unsigned short* C0 = (unsigned short*)(A1 + (size_t)64 * RCAP1_);
    unsigned short* C1 = C0 + (size_t)64 * RCAP0_;
    float* qv1 = (float*)(C1 + (size_t)64 * RCAP1_);
    float* kv1 = qv1 + 16;
    float* qv2 = kv1 + 16;
    float* kv2 = qv2 + 32;
    float* se  = kv2 + 32;

    hipMemsetAsync(cur1, 0, (size_t)(8 * SST1_ + 8 * SST2_ + 128 * CPAD_) * sizeof(int), stream);
    prep_kernel<<<1, 64, 0, stream>>>(Q1, K1, Watt1, Q2, K2, Watt2, We1, We2,
                                      qv1, kv1, qv2, kv2, se);
    split_both<<<2 * SPLITB_, 256, 0, stream>>>(ei0, ew0, ei1, ew1, rcnt0, rcnt1,
                                                A0, C0, A1, C1);
    scatter_bin<<<2048, 256, 0, stream>>>(rcnt0, A0, C0, cur1, ebuf1,
                                          rcnt1, A1, C1, cur2, ebuf2);

    // ---- layer 1 ----
    node_xform1<<<(N1_ + 3) / 4, 256, 0, stream>>>(X, rn0, Wn1, qv1, kv1, S2, S0, aj1, ai1);
    edge_fused1<<<(N1_ + 3) / 4, 256, 0, stream>>>(cur1, ebuf1, S2, S0, aj1, ai1,
                                                   se, batt1, We1, Wc1, bc1, S0);

    // ---- layer 2 ----
    node_xform2<<<(N2_ + 3) / 4, 256, 0, stream>>>(S0, rn1, Wn2, qv2, kv2, S2, S1, aj2, ai2);
    edge_fused2<<<(N2_ + 3) / 4, 256, 0, stream>>>(cur2, ebuf2, S2, S1, aj2, ai2,
                                                   se + 1, batt2, We2, Wc2, bc2, (float*)d_out);
}